// Round 1
// baseline (376.372 us; speedup 1.0000x reference)
//
#include <hip/hip_runtime.h>
#include <hip/hip_bf16.h>

#define HID 128
#define NRAD 16

typedef __attribute__((ext_vector_type(4))) float f32x4;
typedef __attribute__((ext_vector_type(8))) __bf16 bf16x8;
typedef __attribute__((ext_vector_type(8))) unsigned short u16x8;

union F8 { u16x8 u; bf16x8 b; int4 i4; };

__device__ inline unsigned short f2bfbits(float f){
  unsigned int u = __float_as_uint(f);
  u += 0x7FFFu + ((u >> 16) & 1u);   // round-to-nearest-even
  return (unsigned short)(u >> 16);
}

__device__ inline float silu_f(float v){
  return v / (1.0f + __expf(-v));
}

// ---------------------------------------------------------------------------
// P[t][0:128]   = emb[t] @ W1^T + b_lin      (W1 = W_lin[:, 0:128])
// P[t][128:256] = emb[t] @ W2^T              (W2 = W_lin[:, 128:256])
// ---------------------------------------------------------------------------
__global__ void precompute_P(const float* __restrict__ emb,
                             const float* __restrict__ W_lin,
                             const float* __restrict__ b_lin,
                             float* __restrict__ P){
  int t = blockIdx.x;
  int n = threadIdx.x;            // 0..255
  __shared__ float er[HID];
  if (n < HID) er[n] = emb[t * HID + n];
  __syncthreads();
  int half = n >> 7;              // 0 -> P1, 1 -> P2
  int nn   = n & 127;
  const float4* w4 = (const float4*)(W_lin + (size_t)nn * (3 * HID) + half * HID);
  float s = half ? 0.0f : b_lin[nn];
  #pragma unroll 8
  for (int k4 = 0; k4 < HID / 4; ++k4){
    float4 w = w4[k4];
    s += er[k4*4+0]*w.x + er[k4*4+1]*w.y + er[k4*4+2]*w.z + er[k4*4+3]*w.w;
  }
  P[t * 256 + n] = s;
}

// W3bf[n][k] = bf16(W_lin[n][256+k]),  n,k in [0,128)
__global__ void conv_w3(const float* __restrict__ W_lin,
                        unsigned short* __restrict__ W3){
  int idx = blockIdx.x * 256 + threadIdx.x;   // 0..16383
  int n = idx >> 7, k = idx & 127;
  W3[idx] = f2bfbits(W_lin[(size_t)n * (3 * HID) + 2 * HID + k]);
}

// ---------------------------------------------------------------------------
// Fused edge kernel: 64 edges/block, 4 waves (16 edges each), N=128.
//   phase 1: r = silu(rbf @ Wrbf^T + brbf)  -> bf16, XOR-swizzled LDS
//   phase 2: acc = r @ W3^T                 (4 K-steps x 8 N-tiles of MFMA)
//   epilogue: out = silu(acc + P1[x[i]] + P2[x[j]])
// ---------------------------------------------------------------------------
__global__ __launch_bounds__(256) void edge_kernel(
    const float* __restrict__ rbf,
    const int*   __restrict__ ei,
    const int*   __restrict__ ej,
    const int*   __restrict__ x,
    const float* __restrict__ Wrbf,
    const float* __restrict__ brbf,
    const float* __restrict__ P,
    const unsigned short* __restrict__ W3,   // bf16 bits, [128][128]
    float* __restrict__ out,
    int E)
{
  const int tid  = threadIdx.x;
  const int lane = tid & 63;
  const int wv   = tid >> 6;        // wave 0..3
  const int erow = lane & 15;       // A-row / B-col / D-col index
  const int kgrp = lane >> 4;       // 0..3 (K-group)
  const long e0  = (long)blockIdx.x * 64;

  __shared__ int4 rlds[64 * HID * 2 / 16];   // 16 KB swizzled bf16 r-tile
  char* rb = (char*)rlds;

  // ---- phase 1: r tile ----------------------------------------------------
  const long myedge = e0 + wv * 16 + erow;   // this lane's A row (edge)
  F8 fa; fa.i4 = make_int4(0, 0, 0, 0);
  if (kgrp < 2 && myedge < E){
    const float4* s4 = (const float4*)(rbf + myedge * NRAD + kgrp * 8);
    float4 f0 = s4[0], f1 = s4[1];
    fa.u[0]=f2bfbits(f0.x); fa.u[1]=f2bfbits(f0.y); fa.u[2]=f2bfbits(f0.z); fa.u[3]=f2bfbits(f0.w);
    fa.u[4]=f2bfbits(f1.x); fa.u[5]=f2bfbits(f1.y); fa.u[6]=f2bfbits(f1.z); fa.u[7]=f2bfbits(f1.w);
  }
  #pragma unroll
  for (int t = 0; t < 8; ++t){
    F8 fb; fb.i4 = make_int4(0, 0, 0, 0);
    if (kgrp < 2){
      const float4* s4 = (const float4*)(Wrbf + (t * 16 + erow) * NRAD + kgrp * 8);
      float4 f0 = s4[0], f1 = s4[1];
      fb.u[0]=f2bfbits(f0.x); fb.u[1]=f2bfbits(f0.y); fb.u[2]=f2bfbits(f0.z); fb.u[3]=f2bfbits(f0.w);
      fb.u[4]=f2bfbits(f1.x); fb.u[5]=f2bfbits(f1.y); fb.u[6]=f2bfbits(f1.z); fb.u[7]=f2bfbits(f1.w);
    }
    f32x4 acc = {0.f, 0.f, 0.f, 0.f};
    acc = __builtin_amdgcn_mfma_f32_16x16x32_bf16(fa.b, fb.b, acc, 0, 0, 0);
    // D: col (= r's hidden idx n) = t*16+erow ; row (= edge in wave) = kgrp*4+reg
    float bias = brbf[t * 16 + erow];
    #pragma unroll
    for (int r = 0; r < 4; ++r){
      float v = silu_f(acc[r] + bias);
      int e_l  = wv * 16 + kgrp * 4 + r;
      int byte = (e_l << 8) + ((t * 16 + erow) << 1);
      byte ^= (e_l & 7) << 4;
      *(unsigned short*)(rb + byte) = f2bfbits(v);
    }
  }
  __syncthreads();

  // ---- phase 2: r @ W3^T --------------------------------------------------
  f32x4 acc2[8];
  #pragma unroll
  for (int t = 0; t < 8; ++t) acc2[t] = (f32x4){0.f, 0.f, 0.f, 0.f};

  const int e_l = wv * 16 + erow;
  #pragma unroll
  for (int s = 0; s < 4; ++s){
    int byte = (e_l << 8) + ((s * 32 + kgrp * 8) << 1);
    byte ^= (e_l & 7) << 4;
    F8 af; af.i4 = *(const int4*)(rb + byte);
    #pragma unroll
    for (int t = 0; t < 8; ++t){
      F8 bfr; bfr.i4 = *(const int4*)(W3 + (t * 16 + erow) * HID + s * 32 + kgrp * 8);
      acc2[t] = __builtin_amdgcn_mfma_f32_16x16x32_bf16(af.b, bfr.b, acc2[t], 0, 0, 0);
    }
  }

  // ---- epilogue -----------------------------------------------------------
  const long gebase = e0 + wv * 16 + kgrp * 4;
  int ai[4], bi[4];
  #pragma unroll
  for (int r = 0; r < 4; ++r){
    long ge = gebase + r;
    int a = 0, b = 0;
    if (ge < E){ a = x[ei[ge]]; b = x[ej[ge]]; }
    ai[r] = a; bi[r] = b;
  }
  #pragma unroll
  for (int t = 0; t < 8; ++t){
    int n = t * 16 + erow;
    #pragma unroll
    for (int r = 0; r < 4; ++r){
      long ge = gebase + r;
      if (ge < E){
        float v = acc2[t][r] + P[ai[r] * 256 + n] + P[bi[r] * 256 + 128 + n];
        out[ge * HID + n] = silu_f(v);
      }
    }
  }
}

// ---------------------------------------------------------------------------
extern "C" void kernel_launch(void* const* d_in, const int* in_sizes, int n_in,
                              void* d_out, int out_size, void* d_ws, size_t ws_size,
                              hipStream_t stream){
  const int*   x    = (const int*)  d_in[0];
  const float* rbf  = (const float*)d_in[1];
  const int*   ei   = (const int*)  d_in[2];
  const int*   ej   = (const int*)  d_in[3];
  const float* emb  = (const float*)d_in[4];
  const float* Wrbf = (const float*)d_in[5];
  const float* brbf = (const float*)d_in[6];
  const float* Wlin = (const float*)d_in[7];
  const float* blin = (const float*)d_in[8];
  float* out = (float*)d_out;

  const int E      = in_sizes[2];
  const int ntypes = in_sizes[4] / HID;   // 100

  float*          P  = (float*)d_ws;
  unsigned short* W3 = (unsigned short*)((char*)d_ws + (size_t)ntypes * 256 * sizeof(float));

  precompute_P<<<ntypes, 256, 0, stream>>>(emb, Wlin, blin, P);
  conv_w3<<<(HID * HID) / 256, 256, 0, stream>>>(Wlin, W3);

  const int nblk = (int)((E + 63) / 64);
  edge_kernel<<<nblk, 256, 0, stream>>>(rbf, ei, ej, x, Wrbf, brbf, P, W3, out, E);
}

// Round 3
// 355.461 us; speedup vs baseline: 1.0588x; 1.0588x over previous
//
#include <hip/hip_runtime.h>
#include <hip/hip_bf16.h>

#define HID 128
#define NRAD 16

typedef __attribute__((ext_vector_type(4))) float f32x4;
typedef __attribute__((ext_vector_type(8))) __bf16 bf16x8;
typedef __attribute__((ext_vector_type(8))) unsigned short u16x8;

union F8 { u16x8 u; bf16x8 b; int4 i4; };
union B4 { unsigned short u[4]; int2 i2; };

__device__ inline unsigned short f2bfbits(float f){
  unsigned int u = __float_as_uint(f);
  u += 0x7FFFu + ((u >> 16) & 1u);   // round-to-nearest-even
  return (unsigned short)(u >> 16);
}

__device__ inline float silu_f(float v){
  return v * __builtin_amdgcn_rcpf(1.0f + __expf(-v));
}

// ---------------------------------------------------------------------------
// Fused setup:
//   blocks [0, ntypes)            : P[t][0:128]=emb@W1^T+b_lin ; P[t][128:256]=emb@W2^T
//   blocks [ntypes, ntypes+64)    : W3 bf16 conversion  (128x128)
//   blocks [ntypes+64, ntypes+72) : W_rbf bf16 conversion (128x16)
// ---------------------------------------------------------------------------
__global__ void setup_kernel(const float* __restrict__ emb,
                             const float* __restrict__ W_lin,
                             const float* __restrict__ b_lin,
                             const float* __restrict__ W_rbf,
                             int ntypes,
                             float* __restrict__ P,
                             unsigned short* __restrict__ W3,
                             unsigned short* __restrict__ WrbfB){
  int blk = blockIdx.x;
  int n = threadIdx.x;                // 0..255
  if (blk < ntypes){
    __shared__ float er[HID];
    if (n < HID) er[n] = emb[blk * HID + n];
    __syncthreads();
    int half = n >> 7, nn = n & 127;
    const float4* w4 = (const float4*)(W_lin + (size_t)nn * (3 * HID) + half * HID);
    float s = half ? 0.0f : b_lin[nn];
    #pragma unroll 8
    for (int k4 = 0; k4 < HID / 4; ++k4){
      float4 w = w4[k4];
      s += er[k4*4+0]*w.x + er[k4*4+1]*w.y + er[k4*4+2]*w.z + er[k4*4+3]*w.w;
    }
    P[blk * 256 + n] = s;
  } else if (blk < ntypes + 64){
    int idx = (blk - ntypes) * 256 + n;       // 0..16383
    int r = idx >> 7, k = idx & 127;
    W3[idx] = f2bfbits(W_lin[(size_t)r * (3 * HID) + 2 * HID + k]);
  } else {
    int idx = (blk - ntypes - 64) * 256 + n;  // 0..2047 ; W_rbf is [128][16] row-major
    WrbfB[idx] = f2bfbits(W_rbf[idx]);
  }
}

// ---------------------------------------------------------------------------
// Fused edge kernel: 64 edges/block, 4 waves (16 edges each), N=128.
// D-orientation [n][edge]: each lane owns ONE edge and 4 consecutive n.
//   phase 1: r = silu(rbf @ Wrbf^T + brbf)  -> bf16, XOR-swizzled LDS (8B writes)
//   phase 2: acc = W3 * r^T                 (4 K-steps x 8 N-tiles of MFMA)
//   epilogue: out = silu(acc + P1[x[i]] + P2[x[j]])  -- float4 loads+stores
// ---------------------------------------------------------------------------
__global__ __launch_bounds__(256) void edge_kernel(
    const float* __restrict__ rbf,
    const int*   __restrict__ ei,
    const int*   __restrict__ ej,
    const int*   __restrict__ x,
    const unsigned short* __restrict__ WrbfB, // bf16 bits, [128][16]
    const float* __restrict__ brbf,
    const float* __restrict__ P,
    const unsigned short* __restrict__ W3,    // bf16 bits, [128][128]
    float* __restrict__ out,
    int E)
{
  const int tid  = threadIdx.x;
  const int lane = tid & 63;
  const int wv   = tid >> 6;        // wave 0..3
  const int erow = lane & 15;       // this lane's edge-within-wave AND W row idx
  const int kgrp = lane >> 4;       // 0..3 (K-group / D row group)
  const long e0  = (long)blockIdx.x * 64;

  const int  e_l = wv * 16 + erow;  // local edge this lane owns (B col / D col)
  const long ge  = e0 + e_l;        // global edge

  __shared__ char rb[64 * 256];     // 16 KB swizzled bf16 r-tile [64 edges][128 n]

  // ---- phase 1: r tile ----------------------------------------------------
  // B fragment = rbf (cols = edges); only k<16 is real data.
  F8 fbB; fbB.i4 = make_int4(0, 0, 0, 0);
  if (kgrp < 2 && ge < E){
    const f32x4* s4 = (const f32x4*)(rbf + ge * NRAD + kgrp * 8);
    f32x4 f0 = __builtin_nontemporal_load(s4);
    f32x4 f1 = __builtin_nontemporal_load(s4 + 1);
    fbB.u[0]=f2bfbits(f0.x); fbB.u[1]=f2bfbits(f0.y); fbB.u[2]=f2bfbits(f0.z); fbB.u[3]=f2bfbits(f0.w);
    fbB.u[4]=f2bfbits(f1.x); fbB.u[5]=f2bfbits(f1.y); fbB.u[6]=f2bfbits(f1.z); fbB.u[7]=f2bfbits(f1.w);
  }
  #pragma unroll
  for (int t = 0; t < 8; ++t){
    // A fragment = Wrbf rows (n = t*16+erow), k = kgrp*8..+8 (zero beyond k=16)
    F8 fa; fa.i4 = make_int4(0, 0, 0, 0);
    if (kgrp < 2) fa.i4 = *(const int4*)(WrbfB + (t * 16 + erow) * NRAD + kgrp * 8);
    f32x4 acc = {0.f, 0.f, 0.f, 0.f};
    acc = __builtin_amdgcn_mfma_f32_16x16x32_bf16(fa.b, fbB.b, acc, 0, 0, 0);
    // D: col = erow (edge e_l), row = kgrp*4+r  -> n = t*16 + kgrp*4 + r
    float4 bias4 = *(const float4*)(brbf + t * 16 + kgrp * 4);
    B4 pk;
    pk.u[0] = f2bfbits(silu_f(acc[0] + bias4.x));
    pk.u[1] = f2bfbits(silu_f(acc[1] + bias4.y));
    pk.u[2] = f2bfbits(silu_f(acc[2] + bias4.z));
    pk.u[3] = f2bfbits(silu_f(acc[3] + bias4.w));
    int byte = (e_l << 8) + t * 32 + kgrp * 8;
    byte ^= (e_l & 7) << 4;
    *(int2*)(rb + byte) = pk.i2;
  }
  __syncthreads();

  // ---- phase 2: acc = W3 * r^T -------------------------------------------
  f32x4 acc2[8];
  #pragma unroll
  for (int t = 0; t < 8; ++t) acc2[t] = (f32x4){0.f, 0.f, 0.f, 0.f};

  #pragma unroll
  for (int s = 0; s < 4; ++s){
    int byte = (e_l << 8) + s * 64 + kgrp * 16;
    byte ^= (e_l & 7) << 4;
    F8 bB; bB.i4 = *(const int4*)(rb + byte);     // B: col = edge e_l, k = s*32+kgrp*8
    #pragma unroll
    for (int t = 0; t < 8; ++t){
      F8 aW; aW.i4 = *(const int4*)(W3 + (t * 16 + erow) * HID + s * 32 + kgrp * 8);
      acc2[t] = __builtin_amdgcn_mfma_f32_16x16x32_bf16(aW.b, bB.b, acc2[t], 0, 0, 0);
    }
  }

  // ---- epilogue: lane owns edge ge, n = t*16 + kgrp*4 + (0..3) ------------
  int a = 0, b = 0;
  if (ge < E){ a = x[ei[ge]]; b = x[ej[ge]]; }
  const float4* p1 = (const float4*)(P + a * 256);
  const float4* p2 = (const float4*)(P + b * 256 + 128);
  #pragma unroll
  for (int t = 0; t < 8; ++t){
    int nq = t * 4 + kgrp;                        // float4 index of n = t*16+kgrp*4
    float4 v1 = p1[nq];
    float4 v2 = p2[nq];
    f32x4 o;
    o.x = silu_f(acc2[t][0] + v1.x + v2.x);
    o.y = silu_f(acc2[t][1] + v1.y + v2.y);
    o.z = silu_f(acc2[t][2] + v1.z + v2.z);
    o.w = silu_f(acc2[t][3] + v1.w + v2.w);
    if (ge < E)
      __builtin_nontemporal_store(o, (f32x4*)(out + ge * HID + t * 16 + kgrp * 4));
  }
}

// ---------------------------------------------------------------------------
extern "C" void kernel_launch(void* const* d_in, const int* in_sizes, int n_in,
                              void* d_out, int out_size, void* d_ws, size_t ws_size,
                              hipStream_t stream){
  const int*   x    = (const int*)  d_in[0];
  const float* rbf  = (const float*)d_in[1];
  const int*   ei   = (const int*)  d_in[2];
  const int*   ej   = (const int*)  d_in[3];
  const float* emb  = (const float*)d_in[4];
  const float* Wrbf = (const float*)d_in[5];
  const float* brbf = (const float*)d_in[6];
  const float* Wlin = (const float*)d_in[7];
  const float* blin = (const float*)d_in[8];
  float* out = (float*)d_out;

  const int E      = in_sizes[2];
  const int ntypes = in_sizes[4] / HID;   // 100

  float*          P     = (float*)d_ws;
  unsigned short* W3    = (unsigned short*)((char*)d_ws + (size_t)ntypes * 256 * sizeof(float));
  unsigned short* WrbfB = (unsigned short*)((char*)W3 + (size_t)HID * HID * sizeof(unsigned short));

  setup_kernel<<<ntypes + 64 + 8, 256, 0, stream>>>(emb, Wlin, blin, Wrbf, ntypes, P, W3, WrbfB);

  const int nblk = (int)((E + 63) / 64);
  edge_kernel<<<nblk, 256, 0, stream>>>(rbf, ei, ej, x, WrbfB, brbf, P, W3, out, E);
}